// Round 9
// baseline (158.932 us; speedup 1.0000x reference)
//
#include <hip/hip_runtime.h>
#include <math.h>

#define S_LEN    16
#define NTOK     64     // tokens, m = s*4 + b (lane dimension everywhere)
#define DMODEL   512
#define XB_COLS  2176   // x part (2048) + B part (128); z and C parts are dead code
#define ZX_COLS  2240   // XB_COLS + 64 dt columns
#define NCLASS   2513
#define FEATDIM  4096

// ---------------- k_fpart: in_proj partial dots (X transpose fused) --------------
// grid (140, KF) x 256 thr. wave: 4 cols x 64 tokens x (512/KF)-k chunk.
// lane = token m. X rows L2-resident (128KB). Weights via uniform VMEM batches.
__global__ __launch_bounds__(256, 3) void k_fpart(const float* __restrict__ X,
                                                  const float* __restrict__ W,
                                                  float* __restrict__ partF) {
    const int lane = threadIdx.x & 63;
    const int wv   = threadIdx.x >> 6;
    const int KF   = gridDim.y;
    const int kf   = blockIdx.y;
    const int jb   = blockIdx.x * 16 + wv * 4;      // 2240 = 140*16 exact
    const int chunk = DMODEL / KF;                  // floats per k-chunk
    const int nsub  = chunk / 64;

    const int row = (lane & 3) * 16 + (lane >> 2);  // inputs row b*16+s for token m=lane
    const float4* xr = reinterpret_cast<const float4*>(X + (size_t)row * DMODEL);

    const float4* wr[4];
#pragma unroll
    for (int c = 0; c < 4; ++c) {
        const int j = jb + c;
        const int e = (j < XB_COLS) ? (2048 + j) : (2176 + j);
        wr[c] = reinterpret_cast<const float4*>(W + (size_t)e * DMODEL);
    }

    float acc[4] = {0.f, 0.f, 0.f, 0.f};

    for (int s = 0; s < nsub; ++s) {
        const int kq0 = kf * (chunk / 4) + s * 16;
        float4 f[16];
#pragma unroll
        for (int i = 0; i < 16; ++i) f[i] = xr[kq0 + i];
#pragma unroll
        for (int c = 0; c < 4; ++c) {
            float4 w[16];
#pragma unroll
            for (int i = 0; i < 16; ++i) w[i] = wr[c][kq0 + i];
#pragma unroll
            for (int i = 0; i < 16; ++i)
                acc[c] += f[i].x * w[i].x + f[i].y * w[i].y
                        + f[i].z * w[i].z + f[i].w * w[i].w;
        }
    }
#pragma unroll
    for (int c = 0; c < 4; ++c)
        partF[((size_t)kf * ZX_COLS + jb + c) * 64 + lane] = acc[c];
}

// ---------------- k_fepi: reduce partials + conv/silu + dt/dA ---------------------
__global__ __launch_bounds__(256) void k_fepi(const float* __restrict__ partF, int KF,
                                              const float* __restrict__ conv_w,
                                              const float* __restrict__ conv_b,
                                              const float* __restrict__ dt_bias,
                                              const float* __restrict__ A_log,
                                              float* __restrict__ u,
                                              float* __restrict__ aArr,
                                              float* __restrict__ dArr) {
    const int lane = threadIdx.x & 63;                 // token m
    const int j    = blockIdx.x * 4 + (threadIdx.x >> 6);
    float acc = 0.f;
    for (int kf = 0; kf < KF; ++kf)
        acc += partF[((size_t)kf * ZX_COLS + j) * 64 + lane];

    if (j < XB_COLS) {
        const float4 cwv = *reinterpret_cast<const float4*>(conv_w + j * 4);
        const float cb = conv_b[j];
        float wk[4];
        wk[0] = cwv.w;                  // cw[:,0] = conv_w[:,3]
        wk[1] = wk[0] + cwv.z;
        wk[2] = wk[1] + cwv.y;
        wk[3] = wk[2] + cwv.x;
#pragma unroll
        for (int k = 0; k < 4; ++k) {
            const float v = acc * wk[k] + cb;
            u[((size_t)k * NTOK + lane) * XB_COLS + j] = v / (1.f + expf(-v));
        }
    } else {
        const int h = j - XB_COLS;
        const float x = acc + dt_bias[h];
        const float d = (x > 20.f) ? x : log1pf(expf(x));
        dArr[lane * 64 + h] = d;
        aArr[lane * 64 + h] = expf(-d * expf(A_log[h]));
    }
}

// ---------------- k_feats: collapsed SSM -> feats in k-panel layout ---------------
__global__ __launch_bounds__(256) void k_feats(const float* __restrict__ u,
                                               const float* __restrict__ aArr,
                                               const float* __restrict__ dArr,
                                               float* __restrict__ feats_p) {
    const int t = blockIdx.x >> 2;
    const int b = blockIdx.x & 3;
    const int tid = threadIdx.x;
    const int K = 16 - t;          // unroll updates k = 0..K
    const int nvec = t + 5;        // (t+1) scan vectors + 4 unroll vectors

    __shared__ float q[16][64];
    __shared__ float cu[4][64];
    __shared__ float WV[20][32];
    __shared__ float Bv[20][128];

    if (tid < 64) {
        const int h = tid;
        const int mt = t * 4 + b;
        const float a   = aArr[mt * 64 + h];
        const float dtv = dArr[mt * 64 + h];
        float p = 1.f;
        float c3 = 0.f, c2 = 0.f, c1 = 0.f, c0 = 0.f, cs = 0.f;
        for (int j = 0; j <= K + 1; ++j) {     // p = a^j at loop head
            if (j <= K - 3) c3 += p;
            if (j == K - 2) c2 = p;
            if (j == K - 1) c1 = p;
            if (j == K)     c0 = p;
            if (j == K + 1) cs = p;
            p *= a;
        }
        cu[0][h] = dtv * c0;
        cu[1][h] = dtv * c1;
        cu[2][h] = dtv * c2;
        cu[3][h] = dtv * c3;
        float prod = 1.f;
        for (int s = t; s >= 0; --s) {
            const int ms = s * 4 + b;
            q[s][h] = cs * prod * dArr[ms * 64 + h];
            prod *= aArr[ms * 64 + h];
        }
    }
    __syncthreads();

    {   // head-reduced x vectors (32 wide each)
        const int i = tid & 31;
        const int vs = tid >> 5;
        for (int v = vs; v < nvec; v += 8) {
            float acc = 0.f;
            if (v <= t) {
                const float* base = u + (size_t)(v * 4 + b) * XB_COLS;
                for (int h = 0; h < 64; ++h) acc += q[v][h] * base[h * 32 + i];
            } else {
                const int kk = v - t - 1;
                const float* base = u + ((size_t)kk * NTOK + t * 4 + b) * XB_COLS;
                for (int h = 0; h < 64; ++h) acc += cu[kk][h] * base[h * 32 + i];
            }
            WV[v][i] = acc;
        }
    }
    for (int x = tid; x < nvec * 128; x += 256) {
        const int v = x >> 7, n = x & 127;
        size_t src;
        if (v <= t) src = (size_t)(v * 4 + b) * XB_COLS + 2048 + n;
        else        src = ((size_t)(v - t - 1) * NTOK + t * 4 + b) * XB_COLS + 2048 + n;
        Bv[v][n] = u[src];
    }
    __syncthreads();

    {   // rank-nvec outer products -> feats panel [k/4][64 rows][4]
        const int i  = tid >> 3;            // headdim index 0..31
        const int n0 = (tid & 7) * 16;      // state offset
        const int r  = b * 16 + t;          // output row (matches out layout)
        float acc[16];
#pragma unroll
        for (int nn = 0; nn < 16; ++nn) acc[nn] = 0.f;
        for (int v = 0; v < nvec; ++v) {
            const float wvv = WV[v][i];
#pragma unroll
            for (int nn = 0; nn < 16; ++nn) acc[nn] += wvv * Bv[v][n0 + nn];
        }
        float4* fp4 = reinterpret_cast<float4*>(feats_p);
#pragma unroll
        for (int qq = 0; qq < 4; ++qq) {
            const int kq = i * 32 + (tid & 7) * 4 + qq;
            float4 v4;
            v4.x = acc[qq * 4 + 0] * (1.f / 64.f);
            v4.y = acc[qq * 4 + 1] * (1.f / 64.f);
            v4.z = acc[qq * 4 + 2] * (1.f / 64.f);
            v4.w = acc[qq * 4 + 3] * (1.f / 64.f);
            fp4[(size_t)kq * 64 + r] = v4;
        }
    }
}

// ---------------- k_cls: classifier GEMM, weights via uniform VMEM batches --------
// grid (158, KC) x 256 thr. wave: 4 classes x 64 tokens x (4096/KC)-k chunk.
// Per 64-k subtile: 16 coalesced feats float4 (reused x4 classes) + per-class
// batch of 16 uniform weight float4 (deep VMEM clause) + 64 v_fma. No LDS/SMEM.
__global__ __launch_bounds__(256, 3) void k_cls(const float* __restrict__ feats_p,
                                                const float* __restrict__ Wc,
                                                float* __restrict__ partialD) {
    const int lane  = threadIdx.x & 63;
    const int wv    = threadIdx.x >> 6;
    const int KC    = gridDim.y;
    const int kc    = blockIdx.y;
    const int cbase = blockIdx.x * 16 + wv * 4;     // 158*16 = 2528 >= 2513
    const int chunk = FEATDIM / KC;                 // floats per k-chunk
    const int nsub  = chunk / 64;

    const float4* wr[4];
#pragma unroll
    for (int c = 0; c < 4; ++c) {
        int cr = cbase + c; if (cr > NCLASS - 1) cr = NCLASS - 1;
        wr[c] = reinterpret_cast<const float4*>(Wc + (size_t)cr * FEATDIM);
    }

    const float4* fp4 = reinterpret_cast<const float4*>(feats_p);
    float acc[4] = {0.f, 0.f, 0.f, 0.f};

    for (int s = 0; s < nsub; ++s) {
        const int kq0 = kc * (chunk / 4) + s * 16;
        float4 f[16];
#pragma unroll
        for (int i = 0; i < 16; ++i) f[i] = fp4[(size_t)(kq0 + i) * 64 + lane];
#pragma unroll
        for (int c = 0; c < 4; ++c) {
            float4 w[16];
#pragma unroll
            for (int i = 0; i < 16; ++i) w[i] = wr[c][kq0 + i];
#pragma unroll
            for (int i = 0; i < 16; ++i)
                acc[c] += f[i].x * w[i].x + f[i].y * w[i].y
                        + f[i].z * w[i].z + f[i].w * w[i].w;
        }
    }

#pragma unroll
    for (int c = 0; c < 4; ++c) {
        const int cr = cbase + c;
        if (cr < NCLASS)
            partialD[((size_t)kc * NCLASS + cr) * 64 + lane] = acc[c];
    }
}

// ---------------- k_out: reduce split-K partials + bias -> out --------------------
__global__ void k_out(const float* __restrict__ partialD, const float* __restrict__ cls_b,
                      float* __restrict__ out, int KC) {
    const int r  = threadIdx.x & 63;
    const int cl = threadIdx.x >> 6;
    const int c  = blockIdx.x * 4 + cl;
    if (c >= NCLASS) return;
    float s = cls_b[c];
    for (int kc = 0; kc < KC; ++kc)
        s += partialD[((size_t)kc * NCLASS + c) * 64 + r];
    out[(size_t)r * NCLASS + c] = s;
}

// ------------------------------------------------------------------------------
extern "C" void kernel_launch(void* const* d_in, const int* in_sizes, int n_in,
                              void* d_out, int out_size, void* d_ws, size_t ws_size,
                              hipStream_t stream) {
    const float* inputs  = (const float*)d_in[0];
    const float* in_proj = (const float*)d_in[1];
    const float* conv_w  = (const float*)d_in[2];
    const float* conv_b  = (const float*)d_in[3];
    const float* dt_bias = (const float*)d_in[4];
    const float* A_log   = (const float*)d_in[5];
    const float* cls_w   = (const float*)d_in[6];
    const float* cls_b   = (const float*)d_in[7];
    float* out = (float*)d_out;

    float* ws = (float*)d_ws;
    float* aArr    = ws;               //   4096
    float* dArr    = ws + 4096;        //   4096
    float* feats_p = ws + 8192;        // 262144
    float* scr     = ws + 270336;
    float* u       = scr;              // 557056 (dead after k_feats)
    float* partF   = scr + 557056;     // KF*2240*64 (dead after k_fepi)
    float* partialD = scr;             // KC*2513*64 (written after k_feats)

    // tiers: bytes = (270336 + max(557056 + KF*143360, KC*160832)) * 4
    //   KC=8,KF=8 -> 7,897,088   KC=4,KF=4 -> 5,603,328
    int KC, KF;
    if (ws_size >= 7897088u) { KC = 8; KF = 8; }
    else                     { KC = 4; KF = 4; }

    k_fpart <<<dim3(140, KF), 256, 0, stream>>>(inputs, in_proj, partF);
    k_fepi  <<<560, 256, 0, stream>>>(partF, KF, conv_w, conv_b, dt_bias, A_log,
                                      u, aArr, dArr);
    k_feats <<<64, 256, 0, stream>>>(u, aArr, dArr, feats_p);
    k_cls   <<<dim3(158, KC), 256, 0, stream>>>(feats_p, cls_w, partialD);
    k_out   <<<629, 256, 0, stream>>>(partialD, cls_b, out, KC);
}